// Round 11
// baseline (3043.956 us; speedup 1.0000x reference)
//
#include <hip/hip_runtime.h>
#include <hip/hip_bf16.h>

#define B_ 4
#define N_ 16384
#define S_ 1024
#define K_ 32

typedef float f32x2 __attribute__((ext_vector_type(2)));

// wave64 max of nonnegative floats via DPP (identity 0 from bound_ctrl fill).
__device__ __forceinline__ float wave_max_nonneg(float x) {
#define DPPSTEP(ctrl, rm)                                                              \
  {                                                                                    \
    int s_ = __builtin_amdgcn_update_dpp(__float_as_int(x), __float_as_int(x), (ctrl), \
                                         (rm), 0xf, true);                             \
    x = fmaxf(x, __int_as_float(s_));                                                  \
  }
  DPPSTEP(0x111, 0xf)  // row_shr:1
  DPPSTEP(0x112, 0xf)  // row_shr:2
  DPPSTEP(0x114, 0xf)  // row_shr:4
  DPPSTEP(0x118, 0xf)  // row_shr:8
  DPPSTEP(0x142, 0xa)  // row_bcast:15 -> rows 1,3
  DPPSTEP(0x143, 0xc)  // row_bcast:31 -> rows 2,3
#undef DPPSTEP
  return __int_as_float(__builtin_amdgcn_readlane(__float_as_int(x), 63));
}

// wave64 max of u32 (identity 0).
__device__ __forceinline__ unsigned wave_umax(unsigned x) {
#define DPPSTEP(ctrl, rm)                                                             \
  {                                                                                   \
    unsigned s_ = (unsigned)__builtin_amdgcn_update_dpp((int)x, (int)x, (ctrl), (rm), \
                                                        0xf, true);                   \
    x = (x > s_) ? x : s_;                                                            \
  }
  DPPSTEP(0x111, 0xf)
  DPPSTEP(0x112, 0xf)
  DPPSTEP(0x114, 0xf)
  DPPSTEP(0x118, 0xf)
  DPPSTEP(0x142, 0xa)
  DPPSTEP(0x143, 0xc)
#undef DPPSTEP
  return (unsigned)__builtin_amdgcn_readlane((int)x, 63);
}

// ---------------- transpose features [B,64,N] -> [B,N,64] ----------------
__global__ __launch_bounds__(256) void k_transpose(const float* __restrict__ f,
                                                   float* __restrict__ ft) {
  __shared__ float tile[64][65];
  int b = blockIdx.x >> 8;
  int n0 = (blockIdx.x & 255) << 6;
  int t = threadIdx.x;
  int r = t >> 6, c = t & 63;
#pragma unroll
  for (int i = 0; i < 16; ++i) {
    int ch = r + i * 4;
    tile[ch][c] = f[((size_t)b * 64 + ch) * N_ + n0 + c];
  }
  __syncthreads();
#pragma unroll
  for (int i = 0; i < 16; ++i) {
    int n = r + i * 4;
    ft[((size_t)b * N_ + n0 + n) * 64 + c] = tile[c][n];
  }
}

// ---------------- furthest point sampling: 512 threads, 32 pts/thread -------
// R10 skeleton with the post-barrier serial chain minimized:
//  - zero global memory ops inside the loop: `out` staged in 12 KB LDS and
//    flushed once at the end; winner coords published from the WINNER LANE'S
//    REGISTERS as one float4 (no s_x/s_y mirrors, no global z load).
//  - no atomics, no slot reset: every wave always-writes its candidate u64
//    {dist_bits, ~pc} (a wave max always matches >=1 lane), ping-pong by it&1;
//    post-barrier every thread combines the 8 candidates in registers
//    (2x ds_read_b128 + 7 u64 max-selects) and reads one float4 (cxyz).
__global__ __attribute__((amdgpu_flat_work_group_size(512, 512)))
__attribute__((amdgpu_waves_per_eu(2, 2))) void k_fps(const float* __restrict__ xyz,
                                                      float* __restrict__ out) {
#pragma clang fp contract(off)
  const int b = blockIdx.x, t = threadIdx.x;
  const int w = t >> 6;
  const float* X = xyz + (size_t)b * N_ * 3;

  __shared__ float obuf[S_ * 3];                          // 12 KB out staging
  __shared__ __align__(16) unsigned long long cand[2][8]; // per-wave candidates
  __shared__ __align__(16) float4 cxyz[2][8];             // per-wave winner coords

#define FPS_ALLQ(M) \
  M(0) M(1) M(2) M(3) M(4) M(5) M(6) M(7) M(8) M(9) M(10) M(11) M(12) M(13) M(14) M(15)

#define FPS_DECL(q) f32x2 xp##q, yp##q, zp##q, md##q;
  FPS_ALLQ(FPS_DECL)
#undef FPS_DECL

#define FPS_LOAD(q)                                     \
  {                                                     \
    const float* qa = X + (((2 * q) << 9) + t) * 3;     \
    const float* qb = X + (((2 * q + 1) << 9) + t) * 3; \
    xp##q = (f32x2){qa[0], qb[0]};                      \
    yp##q = (f32x2){qa[1], qb[1]};                      \
    zp##q = (f32x2){qa[2], qb[2]};                      \
    md##q = (f32x2){1e10f, 1e10f};                      \
  }
  FPS_ALLQ(FPS_LOAD)
#undef FPS_LOAD

  float c0x = X[0], c0y = X[1], c0z = X[2];
  f32x2 ncx = (f32x2){-c0x, -c0x};
  f32x2 ncy = (f32x2){-c0y, -c0y};
  f32x2 ncz = (f32x2){-c0z, -c0z};
  __syncthreads();

  for (int it = 0;; ++it) {
    if (t == 0) {
      obuf[it * 3 + 0] = -ncx.x;
      obuf[it * 3 + 1] = -ncy.x;
      obuf[it * 3 + 2] = -ncz.x;
    }
    if (it == S_ - 1) break;
    const int pp = it & 1;

    // d = ((dx*dx + dy*dy) + dz*dz) per half; 4 units per asm block.
    // x/y/z are "+v" inout: loop-carried through the asm -> cannot be re-sunk.
    f32x2 ss0, ss1, ss2, ss3, ss4, ss5, ss6, ss7;
    f32x2 ss8, ss9, ss10, ss11, ss12, ss13, ss14, ss15;
#define ASM_UNIT(xs, ys, zs, so)                  \
  "v_pk_add_f32 %[dx], %[" xs "], %[ncx]\n\t"     \
  "v_pk_add_f32 %[dy], %[" ys "], %[ncy]\n\t"     \
  "v_pk_add_f32 %[" so "], %[" zs "], %[ncz]\n\t" \
  "v_pk_mul_f32 %[dx], %[dx], %[dx]\n\t"          \
  "v_pk_mul_f32 %[dy], %[dy], %[dy]\n\t"          \
  "v_pk_mul_f32 %[" so "], %[" so "], %[" so "]\n\t" \
  "v_pk_add_f32 %[dx], %[dx], %[dy]\n\t"          \
  "v_pk_add_f32 %[" so "], %[dx], %[" so "]\n\t"

#define ASM_BLOCK(qa, qb, qc, qd, sa, sb, sc, sd)                                     \
  {                                                                                   \
    f32x2 dx, dy;                                                                     \
    asm(ASM_UNIT("x" #qa, "y" #qa, "z" #qa, "s" #qa)                                  \
        ASM_UNIT("x" #qb, "y" #qb, "z" #qb, "s" #qb)                                  \
        ASM_UNIT("x" #qc, "y" #qc, "z" #qc, "s" #qc)                                  \
        ASM_UNIT("x" #qd, "y" #qd, "z" #qd, "s" #qd)                                  \
        : [s##qa] "=&v"(sa), [s##qb] "=&v"(sb), [s##qc] "=&v"(sc), [s##qd] "=&v"(sd), \
          [dx] "=&v"(dx), [dy] "=&v"(dy), [x##qa] "+v"(xp##qa), [y##qa] "+v"(yp##qa), \
          [z##qa] "+v"(zp##qa), [x##qb] "+v"(xp##qb), [y##qb] "+v"(yp##qb),           \
          [z##qb] "+v"(zp##qb), [x##qc] "+v"(xp##qc), [y##qc] "+v"(yp##qc),           \
          [z##qc] "+v"(zp##qc), [x##qd] "+v"(xp##qd), [y##qd] "+v"(yp##qd),           \
          [z##qd] "+v"(zp##qd)                                                        \
        : [ncx] "v"(ncx), [ncy] "v"(ncy), [ncz] "v"(ncz));                            \
  }
    ASM_BLOCK(0, 1, 2, 3, ss0, ss1, ss2, ss3)
    ASM_BLOCK(4, 5, 6, 7, ss4, ss5, ss6, ss7)
    ASM_BLOCK(8, 9, 10, 11, ss8, ss9, ss10, ss11)
    ASM_BLOCK(12, 13, 14, 15, ss12, ss13, ss14, ss15)
#undef ASM_BLOCK
#undef ASM_UNIT

#define FPS_MIN(q) md##q = __builtin_elementwise_min(md##q, ss##q);
    FPS_ALLQ(FPS_MIN)
#undef FPS_MIN

    // per-thread max tree over 16 pairs
#define PKMAX __builtin_elementwise_max
    f32x2 a0 = PKMAX(PKMAX(md0, md1), PKMAX(md2, md3));
    f32x2 a1 = PKMAX(PKMAX(md4, md5), PKMAX(md6, md7));
    f32x2 a2 = PKMAX(PKMAX(md8, md9), PKMAX(md10, md11));
    f32x2 a3 = PKMAX(PKMAX(md12, md13), PKMAX(md14, md15));
    f32x2 mm = PKMAX(PKMAX(a0, a1), PKMAX(a2, a3));
#undef PKMAX
    float mymax = fmaxf(mm.x, mm.y);

    float wm = wave_max_nonneg(mymax);  // wave max, broadcast

    // first (smallest) slot attaining wm: descending chain, slot = 2q+hi
    int slot = 31;
    if (md15.x == wm) slot = 30;
    if (md14.y == wm) slot = 29;
    if (md14.x == wm) slot = 28;
    if (md13.y == wm) slot = 27;
    if (md13.x == wm) slot = 26;
    if (md12.y == wm) slot = 25;
    if (md12.x == wm) slot = 24;
    if (md11.y == wm) slot = 23;
    if (md11.x == wm) slot = 22;
    if (md10.y == wm) slot = 21;
    if (md10.x == wm) slot = 20;
    if (md9.y == wm) slot = 19;
    if (md9.x == wm) slot = 18;
    if (md8.y == wm) slot = 17;
    if (md8.x == wm) slot = 16;
    if (md7.y == wm) slot = 15;
    if (md7.x == wm) slot = 14;
    if (md6.y == wm) slot = 13;
    if (md6.x == wm) slot = 12;
    if (md5.y == wm) slot = 11;
    if (md5.x == wm) slot = 10;
    if (md4.y == wm) slot = 9;
    if (md4.x == wm) slot = 8;
    if (md3.y == wm) slot = 7;
    if (md3.x == wm) slot = 6;
    if (md2.y == wm) slot = 5;
    if (md2.x == wm) slot = 4;
    if (md1.y == wm) slot = 3;
    if (md1.x == wm) slot = 2;
    if (md0.y == wm) slot = 1;
    if (md0.x == wm) slot = 0;

    unsigned pc = (mymax == wm) ? (((unsigned)slot << 9) | (unsigned)t) : 0xFFFFFFFFu;
    unsigned r = wave_umax(~pc);  // wave winner = min pc (max ~pc)
    if (((~pc) == r) && (pc != 0xFFFFFFFFu)) {  // unique winner lane of this wave
      // publish this wave's candidate + its coords FROM REGISTERS
      int q = slot >> 1;
      f32x2 vx = xp0, vy = yp0, vz = zp0;
      if (q == 1) { vx = xp1; vy = yp1; vz = zp1; }
      if (q == 2) { vx = xp2; vy = yp2; vz = zp2; }
      if (q == 3) { vx = xp3; vy = yp3; vz = zp3; }
      if (q == 4) { vx = xp4; vy = yp4; vz = zp4; }
      if (q == 5) { vx = xp5; vy = yp5; vz = zp5; }
      if (q == 6) { vx = xp6; vy = yp6; vz = zp6; }
      if (q == 7) { vx = xp7; vy = yp7; vz = zp7; }
      if (q == 8) { vx = xp8; vy = yp8; vz = zp8; }
      if (q == 9) { vx = xp9; vy = yp9; vz = zp9; }
      if (q == 10) { vx = xp10; vy = yp10; vz = zp10; }
      if (q == 11) { vx = xp11; vy = yp11; vz = zp11; }
      if (q == 12) { vx = xp12; vy = yp12; vz = zp12; }
      if (q == 13) { vx = xp13; vy = yp13; vz = zp13; }
      if (q == 14) { vx = xp14; vy = yp14; vz = zp14; }
      if (q == 15) { vx = xp15; vy = yp15; vz = zp15; }
      int hi = slot & 1;
      float xc = hi ? vx.y : vx.x;
      float yc = hi ? vy.y : vy.x;
      float zc = hi ? vz.y : vz.x;
      cxyz[pp][w] = make_float4(xc, yc, zc, 0.f);
      cand[pp][w] =
          ((unsigned long long)__float_as_uint(wm) << 32) | (unsigned long long)r;
    }
    __syncthreads();

    // combine the 8 wave candidates in registers (max dist, tie -> min idx)
    const ulonglong2* cp = (const ulonglong2*)&cand[pp][0];
    ulonglong2 A = cp[0], Bp = cp[1], C = cp[2], D = cp[3];
    unsigned long long m0 = (A.x > A.y) ? A.x : A.y;
    unsigned long long m1 = (Bp.x > Bp.y) ? Bp.x : Bp.y;
    unsigned long long m2 = (C.x > C.y) ? C.x : C.y;
    unsigned long long m3 = (D.x > D.y) ? D.x : D.y;
    unsigned long long ma = (m0 > m1) ? m0 : m1;
    unsigned long long mb = (m2 > m3) ? m2 : m3;
    unsigned long long ck = (ma > mb) ? ma : mb;
    unsigned idx = ~((unsigned)(ck & 0xFFFFFFFFull));  // winning pc
    int wstar = (int)((idx >> 6) & 7u);                // winner wave
    float4 cw = cxyz[pp][wstar];
    ncx = (f32x2){-cw.x, -cw.x};
    ncy = (f32x2){-cw.y, -cw.y};
    ncz = (f32x2){-cw.z, -cw.z};
  }
#undef FPS_ALLQ

  // flush staged centers to global (once)
  __syncthreads();
  float* ob = out + (size_t)b * S_ * 3;
  for (int i = t; i < S_ * 3; i += 512) ob[i] = obuf[i];
}

// ---------------- ball query: 1 wave per center ----------------
__global__ __launch_bounds__(256) void k_ball(const float* __restrict__ xyz,
                                              const float* __restrict__ nx,
                                              int* __restrict__ bidx) {
#pragma clang fp contract(off)
  int gw = (blockIdx.x * 256 + threadIdx.x) >> 6;
  int l = threadIdx.x & 63;
  int b = gw >> 10;
  const float* X = xyz + (size_t)b * N_ * 3;
  float cx = nx[(size_t)gw * 3 + 0], cy = nx[(size_t)gw * 3 + 1], cz = nx[(size_t)gw * 3 + 2];
  float xn2 = (cx * cx + cy * cy) + cz * cz;
  int* out = bidx + gw * K_;
  int have = 0, first = -1;
  for (int n0 = 0; n0 < N_; n0 += 64) {
    int p = n0 + l;
    float x = X[p * 3 + 0], y = X[p * 3 + 1], z = X[p * 3 + 2];
    float pn2 = (x * x + y * y) + z * z;
    float dt = (x * cx + y * cy) + z * cz;
    float d2 = (xn2 + pn2) - 2.0f * dt;  // exact replica of ref's expanded form
    unsigned long long m = __ballot(d2 < 0.039999999105930328f);  // float(0.04), NOT 0.2f*0.2f
    if (first < 0 && m) first = n0 + (__ffsll(m) - 1);
    if (m & (1ull << l)) {
      int pos = have + __popcll(m & ((1ull << l) - 1ull));
      if (pos < K_) out[pos] = p;
    }
    have += __popcll(m);
    if (have >= K_) break;
  }
  if (have < K_ && l >= have && l < K_) out[l] = first;  // pad with first neighbor
}

// ---------------- gather + conv1 (67 -> 64), 8 centers per block ----------------
__global__ __launch_bounds__(256) void k_conv1(const float* __restrict__ xyz,
                                               const float* __restrict__ ft,
                                               const float* __restrict__ nx,
                                               const int* __restrict__ bidx,
                                               const float* __restrict__ W0,
                                               float* __restrict__ y1) {
  __shared__ float w0t[67][64];
  __shared__ float Xs[32][69];  // stride 69: (69k+i)%32 = (5k+i)%32 conflict-free
  __shared__ int lidx[32];
  __shared__ float lctr[3];
  const int t = threadIdx.x;
  for (int idx = t; idx < 67 * 64; idx += 256) {
    int i = idx >> 6, c = idx & 63;
    w0t[i][c] = W0[c * 67 + i];
  }
  const int k = t & 31, cb = (t >> 5) << 3;
  const int gk = t >> 3, c8 = (t & 7) << 3;
  for (int cc = 0; cc < 8; ++cc) {
    int cs = blockIdx.x * 8 + cc;
    int b = cs >> 10;
    __syncthreads();
    if (t < 32) lidx[t] = bidx[cs * K_ + t];
    if (t < 3) lctr[t] = nx[(size_t)cs * 3 + t];
    __syncthreads();
    {
      int p = lidx[gk];
      const float* src = ft + ((size_t)b * N_ + p) * 64 + c8;
      float4 v0 = *(const float4*)src;
      float4 v1 = *(const float4*)(src + 4);
      float* xr = &Xs[gk][3 + c8];
      xr[0] = v0.x; xr[1] = v0.y; xr[2] = v0.z; xr[3] = v0.w;
      xr[4] = v1.x; xr[5] = v1.y; xr[6] = v1.z; xr[7] = v1.w;
    }
    if (t < 32) {
      int p = lidx[t];
      const float* pp = xyz + ((size_t)b * N_ + p) * 3;
      Xs[t][0] = pp[0] - lctr[0];
      Xs[t][1] = pp[1] - lctr[1];
      Xs[t][2] = pp[2] - lctr[2];
    }
    __syncthreads();
    float acc[8] = {};
    for (int i = 0; i < 67; ++i) {
      float xv = Xs[k][i];
      const float4 wa = *(const float4*)&w0t[i][cb];
      const float4 wb = *(const float4*)&w0t[i][cb + 4];
      acc[0] = fmaf(wa.x, xv, acc[0]);
      acc[1] = fmaf(wa.y, xv, acc[1]);
      acc[2] = fmaf(wa.z, xv, acc[2]);
      acc[3] = fmaf(wa.w, xv, acc[3]);
      acc[4] = fmaf(wb.x, xv, acc[4]);
      acc[5] = fmaf(wb.y, xv, acc[5]);
      acc[6] = fmaf(wb.z, xv, acc[6]);
      acc[7] = fmaf(wb.w, xv, acc[7]);
    }
    float* dst = y1 + ((size_t)cs * K_ + k) * 64 + cb;
    *(float4*)dst = make_float4(acc[0], acc[1], acc[2], acc[3]);
    *(float4*)(dst + 4) = make_float4(acc[4], acc[5], acc[6], acc[7]);
  }
}

// ---------------- BN1 stats: per-block partials (deterministic) ----------------
__global__ __launch_bounds__(256) void k_stats1(const float* __restrict__ y1,
                                                float* __restrict__ part) {
  int t = threadIdx.x;
  int c = t & 63;
  float s = 0.f, q = 0.f;
  for (int row = blockIdx.x * 4 + (t >> 6); row < B_ * S_ * K_; row += 512 * 4) {
    float v = y1[(size_t)row * 64 + c];
    s += v;
    q = fmaf(v, v, q);
  }
  __shared__ float ls[4][64], lq[4][64];
  ls[t >> 6][c] = s;
  lq[t >> 6][c] = q;
  __syncthreads();
  if (t < 64) {
    float S = (ls[0][t] + ls[1][t]) + (ls[2][t] + ls[3][t]);
    float Q = (lq[0][t] + lq[1][t]) + (lq[2][t] + lq[3][t]);
    part[blockIdx.x * 128 + t] = S;
    part[blockIdx.x * 128 + 64 + t] = Q;
  }
}

// ---------------- reduce [nrow][ncol] partials -> [ncol] ----------------
__global__ void k_red(const float* __restrict__ part, float* __restrict__ outv,
                      int ncol, int nrow) {
  int c = blockIdx.x * 64 + threadIdx.x;
  float a0 = 0, a1 = 0, a2 = 0, a3 = 0;
  for (int r = 0; r < nrow; r += 4) {
    a0 += part[(size_t)(r + 0) * ncol + c];
    a1 += part[(size_t)(r + 1) * ncol + c];
    a2 += part[(size_t)(r + 2) * ncol + c];
    a3 += part[(size_t)(r + 3) * ncol + c];
  }
  outv[c] = (a0 + a1) + (a2 + a3);
}

// ------- BN1-apply + conv2 (64->128) + stats2 partials + max/min over K -------
__global__ __launch_bounds__(256) void k_conv2(const float* __restrict__ y1,
                                               const float* __restrict__ W1,
                                               const float* __restrict__ st1,
                                               const float* __restrict__ g0,
                                               const float* __restrict__ b0,
                                               float* __restrict__ part2,
                                               float* __restrict__ mmax,
                                               float* __restrict__ mmin) {
  __shared__ float w1t[64][128];
  __shared__ float X2[32][69];
  __shared__ float a1s[64], bb1s[64];
  const int t = threadIdx.x;
  if (t < 64) {
    float s = st1[t], q = st1[64 + t];
    float m = s * (1.f / 131072.f);
    float v = fmaxf(q * (1.f / 131072.f) - m * m, 0.f);
    float inv = 1.f / sqrtf(v + 1e-5f);
    float a = g0[t] * inv;
    a1s[t] = a;
    bb1s[t] = b0[t] - m * a;
  }
  for (int idx = t; idx < 64 * 128; idx += 256) {
    int i = idx >> 7, c = idx & 127;
    w1t[i][c] = W1[c * 64 + i];
  }
  const int kg = (t & 7) << 2;   // 4 neighbor slots
  const int cb = (t >> 3) << 2;  // 4 channels
  const int gk = t >> 3, c8 = (t & 7) << 3;
  float ts[4] = {}, tq[4] = {};
  for (int cc = 0; cc < 8; ++cc) {
    int cs = blockIdx.x * 8 + cc;
    int b = cs >> 10, sc = cs & 1023;
    __syncthreads();
    {
      const float* src = y1 + ((size_t)cs * K_ + gk) * 64 + c8;
      float4 v0 = *(const float4*)src;
      float4 v1 = *(const float4*)(src + 4);
      float vv[8] = {v0.x, v0.y, v0.z, v0.w, v1.x, v1.y, v1.z, v1.w};
#pragma unroll
      for (int j = 0; j < 8; ++j) {
        int c = c8 + j;
        X2[gk][c] = fmaxf(fmaf(a1s[c], vv[j], bb1s[c]), 0.f);
      }
    }
    __syncthreads();
    float acc[4][4] = {};
    for (int i = 0; i < 64; ++i) {
      const float4 w = *(const float4*)&w1t[i][cb];
#pragma unroll
      for (int kk = 0; kk < 4; ++kk) {
        float xv = X2[kg + kk][i];
        acc[kk][0] = fmaf(w.x, xv, acc[kk][0]);
        acc[kk][1] = fmaf(w.y, xv, acc[kk][1]);
        acc[kk][2] = fmaf(w.z, xv, acc[kk][2]);
        acc[kk][3] = fmaf(w.w, xv, acc[kk][3]);
      }
    }
    float mx[4], mn[4];
#pragma unroll
    for (int j = 0; j < 4; ++j) {
      mx[j] = fmaxf(fmaxf(acc[0][j], acc[1][j]), fmaxf(acc[2][j], acc[3][j]));
      mn[j] = fminf(fminf(acc[0][j], acc[1][j]), fminf(acc[2][j], acc[3][j]));
      ts[j] += (acc[0][j] + acc[1][j]) + (acc[2][j] + acc[3][j]);
      tq[j] += (acc[0][j] * acc[0][j] + acc[1][j] * acc[1][j]) +
               (acc[2][j] * acc[2][j] + acc[3][j] * acc[3][j]);
    }
#pragma unroll
    for (int off = 1; off < 8; off <<= 1) {
#pragma unroll
      for (int j = 0; j < 4; ++j) {
        mx[j] = fmaxf(mx[j], __shfl_xor(mx[j], off));
        mn[j] = fminf(mn[j], __shfl_xor(mn[j], off));
      }
    }
    if ((t & 7) == 0) {
#pragma unroll
      for (int j = 0; j < 4; ++j) {
        size_t o = ((size_t)b * 128 + cb + j) * 1024 + sc;
        mmax[o] = mx[j];
        mmin[o] = mn[j];
      }
    }
  }
#pragma unroll
  for (int off = 1; off < 8; off <<= 1) {
#pragma unroll
    for (int j = 0; j < 4; ++j) {
      ts[j] += __shfl_xor(ts[j], off);
      tq[j] += __shfl_xor(tq[j], off);
    }
  }
  if ((t & 7) == 0) {
#pragma unroll
    for (int j = 0; j < 4; ++j) {
      part2[blockIdx.x * 256 + cb + j] = ts[j];
      part2[blockIdx.x * 256 + 128 + cb + j] = tq[j];
    }
  }
}

// ---------------- finalize: BN2 affine on max/min + ReLU ----------------
__global__ __launch_bounds__(256) void k_final(const float* __restrict__ st2,
                                               const float* __restrict__ g1,
                                               const float* __restrict__ b1,
                                               const float* __restrict__ mmax,
                                               const float* __restrict__ mmin,
                                               float* __restrict__ out) {
  int tid = blockIdx.x * 256 + threadIdx.x;
  int c = (tid >> 10) & 127;
  float s = st2[c], q = st2[128 + c];
  float m = s * (1.f / 131072.f);
  float v = fmaxf(q * (1.f / 131072.f) - m * m, 0.f);
  float inv = 1.f / sqrtf(v + 1e-5f);
  float a = g1[c] * inv;
  float bb = b1[c] - m * a;
  // max over K of relu(a*x+bb) == relu(a * (a>=0 ? max : min) + bb)
  float x = (a >= 0.f) ? mmax[tid] : mmin[tid];
  out[12288 + tid] = fmaxf(fmaf(a, x, bb), 0.f);
}

extern "C" void kernel_launch(void* const* d_in, const int* in_sizes, int n_in,
                              void* d_out, int out_size, void* d_ws, size_t ws_size,
                              hipStream_t stream) {
  const float* xyz = (const float*)d_in[0];
  const float* features = (const float*)d_in[1];
  const float* W0 = (const float*)d_in[2];
  const float* g0 = (const float*)d_in[3];
  const float* b0 = (const float*)d_in[4];
  const float* W1 = (const float*)d_in[5];
  const float* g1 = (const float*)d_in[6];
  const float* b1 = (const float*)d_in[7];
  float* out = (float*)d_out;
  float* ws = (float*)d_ws;

  float* ft = ws;                                   // 4,194,304 f
  float* y1 = ft + (size_t)4 * 16384 * 64;          // 8,388,608 f
  float* part1 = y1 + (size_t)4 * 1024 * 32 * 64;   // 65,536 f
  float* part2 = part1 + 512 * 128;                 // 131,072 f
  float* st1 = part2 + 512 * 256;                   // 128 f
  float* st2 = st1 + 128;                           // 256 f
  float* mmax = st2 + 256;                          // 524,288 f
  float* mmin = mmax + (size_t)4 * 128 * 1024;      // 524,288 f
  int* bidx = (int*)(mmin + (size_t)4 * 128 * 1024);// 131,072 i
  if (ws_size < (size_t)(13828480 + 131072) * 4) return;  // workspace guard

  float* nxyz = out;  // new_xyz occupies out[0..12288)

  k_transpose<<<1024, 256, 0, stream>>>(features, ft);
  k_fps<<<4, 512, 0, stream>>>(xyz, nxyz);
  k_ball<<<1024, 256, 0, stream>>>(xyz, nxyz, bidx);
  k_conv1<<<512, 256, 0, stream>>>(xyz, ft, nxyz, bidx, W0, y1);
  k_stats1<<<512, 256, 0, stream>>>(y1, part1);
  k_red<<<2, 64, 0, stream>>>(part1, st1, 128, 512);
  k_conv2<<<512, 256, 0, stream>>>(y1, W1, st1, g0, b0, part2, mmax, mmin);
  k_red<<<4, 64, 0, stream>>>(part2, st2, 256, 512);
  k_final<<<2048, 256, 0, stream>>>(st2, g1, b1, mmax, mmin, out);
}

// Round 12
// 2086.497 us; speedup vs baseline: 1.4589x; 1.4589x over previous
//
#include <hip/hip_runtime.h>
#include <hip/hip_bf16.h>

#define B_ 4
#define N_ 16384
#define S_ 1024
#define K_ 32

typedef float f32x2 __attribute__((ext_vector_type(2)));

// wave64 max of nonnegative floats via DPP (identity 0 from bound_ctrl fill).
__device__ __forceinline__ float wave_max_nonneg(float x) {
#define DPPSTEP(ctrl, rm)                                                              \
  {                                                                                    \
    int s_ = __builtin_amdgcn_update_dpp(__float_as_int(x), __float_as_int(x), (ctrl), \
                                         (rm), 0xf, true);                             \
    x = fmaxf(x, __int_as_float(s_));                                                  \
  }
  DPPSTEP(0x111, 0xf)  // row_shr:1
  DPPSTEP(0x112, 0xf)  // row_shr:2
  DPPSTEP(0x114, 0xf)  // row_shr:4
  DPPSTEP(0x118, 0xf)  // row_shr:8
  DPPSTEP(0x142, 0xa)  // row_bcast:15 -> rows 1,3
  DPPSTEP(0x143, 0xc)  // row_bcast:31 -> rows 2,3
#undef DPPSTEP
  return __int_as_float(__builtin_amdgcn_readlane(__float_as_int(x), 63));
}

// wave64 max of u32 (identity 0).
__device__ __forceinline__ unsigned wave_umax(unsigned x) {
#define DPPSTEP(ctrl, rm)                                                             \
  {                                                                                   \
    unsigned s_ = (unsigned)__builtin_amdgcn_update_dpp((int)x, (int)x, (ctrl), (rm), \
                                                        0xf, true);                   \
    x = (x > s_) ? x : s_;                                                            \
  }
  DPPSTEP(0x111, 0xf)
  DPPSTEP(0x112, 0xf)
  DPPSTEP(0x114, 0xf)
  DPPSTEP(0x118, 0xf)
  DPPSTEP(0x142, 0xa)
  DPPSTEP(0x143, 0xc)
#undef DPPSTEP
  return (unsigned)__builtin_amdgcn_readlane((int)x, 63);
}

// ---------------- transpose features [B,64,N] -> [B,N,64] ----------------
__global__ __launch_bounds__(256) void k_transpose(const float* __restrict__ f,
                                                   float* __restrict__ ft) {
  __shared__ float tile[64][65];
  int b = blockIdx.x >> 8;
  int n0 = (blockIdx.x & 255) << 6;
  int t = threadIdx.x;
  int r = t >> 6, c = t & 63;
#pragma unroll
  for (int i = 0; i < 16; ++i) {
    int ch = r + i * 4;
    tile[ch][c] = f[((size_t)b * 64 + ch) * N_ + n0 + c];
  }
  __syncthreads();
#pragma unroll
  for (int i = 0; i < 16; ++i) {
    int n = r + i * 4;
    ft[((size_t)b * N_ + n0 + n) * 64 + c] = tile[c][n];
  }
}

// ---------------- furthest point sampling: 1 block per batch ----------------
// Round-9 skeleton (passed) with the UPD core made PURE-VALU on pinned
// registers: xy moved from LDS into registers held live by "+v" asm operands
// (loop-carried through the asm -> cannot be sunk or rematerialized). Total
// state 16 md + 16 z + 32 xy + temps ~= 105 VGPR < 128 budget at 4 waves/EU —
// under the no-spill line (round 6 was spill-free at 52; rounds 10/11 spilled
// at 175+). LDS keeps only the s_x/s_y mirrors for the once-per-iteration
// winner-coordinate decode. This deletes the ~1024 cyc/iter LDS-BW term from
// the round-6 floor decomposition while keeping the proven argmax intact.
__global__ __attribute__((amdgpu_flat_work_group_size(1024, 1024)))
__attribute__((amdgpu_waves_per_eu(4, 4))) void k_fps(const float* __restrict__ xyz,
                                                      float* __restrict__ out) {
#pragma clang fp contract(off)
  const int b = blockIdx.x, t = threadIdx.x;
  const float* X = xyz + (size_t)b * N_ * 3;

  __shared__ f32x2 s_x[8192];               // 64 KB mirror {x_a, x_b}, entry (q<<10)+t
  __shared__ f32x2 s_y[8192];               // 64 KB mirror {y_a, y_b}
  __shared__ unsigned long long slot64[2];  // ping-pong argmax slots

  f32x2 xp0, xp1, xp2, xp3, xp4, xp5, xp6, xp7;
  f32x2 yp0, yp1, yp2, yp3, yp4, yp5, yp6, yp7;
  f32x2 pz0, pz1, pz2, pz3, pz4, pz5, pz6, pz7;
  f32x2 md0, md1, md2, md3, md4, md5, md6, md7;
  md0 = md1 = md2 = md3 = md4 = md5 = md6 = md7 = (f32x2){1e10f, 1e10f};

#define FPS_LOAD(q)                                      \
  {                                                      \
    const float* qa = X + (((2 * q) << 10) + t) * 3;     \
    const float* qb = X + (((2 * q + 1) << 10) + t) * 3; \
    xp##q = (f32x2){qa[0], qb[0]};                       \
    yp##q = (f32x2){qa[1], qb[1]};                       \
    pz##q = (f32x2){qa[2], qb[2]};                       \
    s_x[(q << 10) + t] = xp##q;                          \
    s_y[(q << 10) + t] = yp##q;                          \
  }
  FPS_LOAD(0)
  FPS_LOAD(1)
  FPS_LOAD(2)
  FPS_LOAD(3)
  FPS_LOAD(4)
  FPS_LOAD(5)
  FPS_LOAD(6)
  FPS_LOAD(7)
#undef FPS_LOAD

  float c0x = X[0], c0y = X[1], c0z = X[2];
  f32x2 ncx = (f32x2){-c0x, -c0x};
  f32x2 ncy = (f32x2){-c0y, -c0y};
  f32x2 ncz = (f32x2){-c0z, -c0z};
  if (t == 0) { slot64[0] = 0ull; slot64[1] = 0ull; }
  __syncthreads();

  int sld = 0;
  for (int it = 0;; ++it) {
    if (t == 0) {
      float* o = out + ((size_t)b * S_ + it) * 3;
      o[0] = -ncx.x; o[1] = -ncy.x; o[2] = -ncz.x;
    }
    if (it == S_ - 1) break;

    // d = ((dx*dx + dy*dy) + dz*dz) per half; pure VALU on pinned registers.
    f32x2 ss0, ss1, ss2, ss3, ss4, ss5, ss6, ss7;
#define ASM_UNIT(xs, ys, zs, so)                     \
  "v_pk_add_f32 %[dx], %[" xs "], %[ncx]\n\t"        \
  "v_pk_add_f32 %[dy], %[" ys "], %[ncy]\n\t"        \
  "v_pk_add_f32 %[" so "], %[" zs "], %[ncz]\n\t"    \
  "v_pk_mul_f32 %[dx], %[dx], %[dx]\n\t"             \
  "v_pk_mul_f32 %[dy], %[dy], %[dy]\n\t"             \
  "v_pk_mul_f32 %[" so "], %[" so "], %[" so "]\n\t" \
  "v_pk_add_f32 %[dx], %[dx], %[dy]\n\t"             \
  "v_pk_add_f32 %[" so "], %[dx], %[" so "]\n\t"

#define ASM_BLOCK(qa, qb, qc, qd, sa, sb, sc, sd)                                     \
  {                                                                                   \
    f32x2 dx, dy;                                                                     \
    asm(ASM_UNIT("x" #qa, "y" #qa, "z" #qa, "s" #qa)                                  \
        ASM_UNIT("x" #qb, "y" #qb, "z" #qb, "s" #qb)                                  \
        ASM_UNIT("x" #qc, "y" #qc, "z" #qc, "s" #qc)                                  \
        ASM_UNIT("x" #qd, "y" #qd, "z" #qd, "s" #qd)                                  \
        : [s##qa] "=&v"(sa), [s##qb] "=&v"(sb), [s##qc] "=&v"(sc), [s##qd] "=&v"(sd), \
          [dx] "=&v"(dx), [dy] "=&v"(dy), [x##qa] "+v"(xp##qa), [y##qa] "+v"(yp##qa), \
          [z##qa] "+v"(pz##qa), [x##qb] "+v"(xp##qb), [y##qb] "+v"(yp##qb),           \
          [z##qb] "+v"(pz##qb), [x##qc] "+v"(xp##qc), [y##qc] "+v"(yp##qc),           \
          [z##qc] "+v"(pz##qc), [x##qd] "+v"(xp##qd), [y##qd] "+v"(yp##qd),           \
          [z##qd] "+v"(pz##qd)                                                        \
        : [ncx] "v"(ncx), [ncy] "v"(ncy), [ncz] "v"(ncz));                            \
  }
    ASM_BLOCK(0, 1, 2, 3, ss0, ss1, ss2, ss3)
    ASM_BLOCK(4, 5, 6, 7, ss4, ss5, ss6, ss7)
#undef ASM_BLOCK
#undef ASM_UNIT

    md0 = __builtin_elementwise_min(md0, ss0);
    md1 = __builtin_elementwise_min(md1, ss1);
    md2 = __builtin_elementwise_min(md2, ss2);
    md3 = __builtin_elementwise_min(md3, ss3);
    md4 = __builtin_elementwise_min(md4, ss4);
    md5 = __builtin_elementwise_min(md5, ss5);
    md6 = __builtin_elementwise_min(md6, ss6);
    md7 = __builtin_elementwise_min(md7, ss7);

    // per-thread max via packed tree (7 pk_max + 1 scalar)
    f32x2 m01 = __builtin_elementwise_max(md0, md1);
    f32x2 m23 = __builtin_elementwise_max(md2, md3);
    f32x2 m45 = __builtin_elementwise_max(md4, md5);
    f32x2 m67 = __builtin_elementwise_max(md6, md7);
    f32x2 m03 = __builtin_elementwise_max(m01, m23);
    f32x2 m47 = __builtin_elementwise_max(m45, m67);
    f32x2 mm = __builtin_elementwise_max(m03, m47);
    float mymax = fmaxf(mm.x, mm.y);

    float wm = wave_max_nonneg(mymax);  // wave max, broadcast

    // first (smallest) slot attaining wm: descending chain, slot = 2q+hi
    int slot = 15;
    if (md7.x == wm) slot = 14;
    if (md6.y == wm) slot = 13;
    if (md6.x == wm) slot = 12;
    if (md5.y == wm) slot = 11;
    if (md5.x == wm) slot = 10;
    if (md4.y == wm) slot = 9;
    if (md4.x == wm) slot = 8;
    if (md3.y == wm) slot = 7;
    if (md3.x == wm) slot = 6;
    if (md2.y == wm) slot = 5;
    if (md2.x == wm) slot = 4;
    if (md1.y == wm) slot = 3;
    if (md1.x == wm) slot = 2;
    if (md0.y == wm) slot = 1;
    if (md0.x == wm) slot = 0;
    unsigned pc = (mymax == wm) ? (((unsigned)slot << 10) | (unsigned)t) : 0xFFFFFFFFu;
    unsigned r = wave_umax(~pc);  // wave winner = min pc (max ~pc)
    if (((~pc) == r) && (pc != 0xFFFFFFFFu)) {  // unique winner lane of this wave
      unsigned long long packed =
          ((unsigned long long)__float_as_uint(wm) << 32) | (unsigned long long)r;
      atomicMax(&slot64[sld], packed);  // block winner: max dist, tie -> min idx
    }
    if (t == 0) slot64[sld ^ 1] = 0ull;  // reset next slot before the barrier
    __syncthreads();

    unsigned long long pkv = slot64[sld];
    unsigned idx = ~((unsigned)(pkv & 0xFFFFFFFFull));  // winning global point index
    int q = (int)(idx >> 11);
    int hi = (int)(idx >> 10) & 1;
    int tt = (int)(idx & 1023u);
    f32x2 vx = s_x[(q << 10) + tt];  // broadcast LDS reads
    f32x2 vy = s_y[(q << 10) + tt];
    float zc = X[3 * (int)idx + 2];  // uniform scalar load (L2-hot)
    float xc = hi ? vx.y : vx.x;
    float yc = hi ? vy.y : vy.x;
    ncx = (f32x2){-xc, -xc};
    ncy = (f32x2){-yc, -yc};
    ncz = (f32x2){-zc, -zc};
    sld ^= 1;
  }
}

// ---------------- ball query: 1 wave per center ----------------
__global__ __launch_bounds__(256) void k_ball(const float* __restrict__ xyz,
                                              const float* __restrict__ nx,
                                              int* __restrict__ bidx) {
#pragma clang fp contract(off)
  int gw = (blockIdx.x * 256 + threadIdx.x) >> 6;
  int l = threadIdx.x & 63;
  int b = gw >> 10;
  const float* X = xyz + (size_t)b * N_ * 3;
  float cx = nx[(size_t)gw * 3 + 0], cy = nx[(size_t)gw * 3 + 1], cz = nx[(size_t)gw * 3 + 2];
  float xn2 = (cx * cx + cy * cy) + cz * cz;
  int* out = bidx + gw * K_;
  int have = 0, first = -1;
  for (int n0 = 0; n0 < N_; n0 += 64) {
    int p = n0 + l;
    float x = X[p * 3 + 0], y = X[p * 3 + 1], z = X[p * 3 + 2];
    float pn2 = (x * x + y * y) + z * z;
    float dt = (x * cx + y * cy) + z * cz;
    float d2 = (xn2 + pn2) - 2.0f * dt;  // exact replica of ref's expanded form
    unsigned long long m = __ballot(d2 < 0.039999999105930328f);  // float(0.04), NOT 0.2f*0.2f
    if (first < 0 && m) first = n0 + (__ffsll(m) - 1);
    if (m & (1ull << l)) {
      int pos = have + __popcll(m & ((1ull << l) - 1ull));
      if (pos < K_) out[pos] = p;
    }
    have += __popcll(m);
    if (have >= K_) break;
  }
  if (have < K_ && l >= have && l < K_) out[l] = first;  // pad with first neighbor
}

// ---------------- gather + conv1 (67 -> 64), 8 centers per block ----------------
__global__ __launch_bounds__(256) void k_conv1(const float* __restrict__ xyz,
                                               const float* __restrict__ ft,
                                               const float* __restrict__ nx,
                                               const int* __restrict__ bidx,
                                               const float* __restrict__ W0,
                                               float* __restrict__ y1) {
  __shared__ float w0t[67][64];
  __shared__ float Xs[32][69];  // stride 69: (69k+i)%32 = (5k+i)%32 conflict-free
  __shared__ int lidx[32];
  __shared__ float lctr[3];
  const int t = threadIdx.x;
  for (int idx = t; idx < 67 * 64; idx += 256) {
    int i = idx >> 6, c = idx & 63;
    w0t[i][c] = W0[c * 67 + i];
  }
  const int k = t & 31, cb = (t >> 5) << 3;
  const int gk = t >> 3, c8 = (t & 7) << 3;
  for (int cc = 0; cc < 8; ++cc) {
    int cs = blockIdx.x * 8 + cc;
    int b = cs >> 10;
    __syncthreads();
    if (t < 32) lidx[t] = bidx[cs * K_ + t];
    if (t < 3) lctr[t] = nx[(size_t)cs * 3 + t];
    __syncthreads();
    {
      int p = lidx[gk];
      const float* src = ft + ((size_t)b * N_ + p) * 64 + c8;
      float4 v0 = *(const float4*)src;
      float4 v1 = *(const float4*)(src + 4);
      float* xr = &Xs[gk][3 + c8];
      xr[0] = v0.x; xr[1] = v0.y; xr[2] = v0.z; xr[3] = v0.w;
      xr[4] = v1.x; xr[5] = v1.y; xr[6] = v1.z; xr[7] = v1.w;
    }
    if (t < 32) {
      int p = lidx[t];
      const float* pp = xyz + ((size_t)b * N_ + p) * 3;
      Xs[t][0] = pp[0] - lctr[0];
      Xs[t][1] = pp[1] - lctr[1];
      Xs[t][2] = pp[2] - lctr[2];
    }
    __syncthreads();
    float acc[8] = {};
    for (int i = 0; i < 67; ++i) {
      float xv = Xs[k][i];
      const float4 wa = *(const float4*)&w0t[i][cb];
      const float4 wb = *(const float4*)&w0t[i][cb + 4];
      acc[0] = fmaf(wa.x, xv, acc[0]);
      acc[1] = fmaf(wa.y, xv, acc[1]);
      acc[2] = fmaf(wa.z, xv, acc[2]);
      acc[3] = fmaf(wa.w, xv, acc[3]);
      acc[4] = fmaf(wb.x, xv, acc[4]);
      acc[5] = fmaf(wb.y, xv, acc[5]);
      acc[6] = fmaf(wb.z, xv, acc[6]);
      acc[7] = fmaf(wb.w, xv, acc[7]);
    }
    float* dst = y1 + ((size_t)cs * K_ + k) * 64 + cb;
    *(float4*)dst = make_float4(acc[0], acc[1], acc[2], acc[3]);
    *(float4*)(dst + 4) = make_float4(acc[4], acc[5], acc[6], acc[7]);
  }
}

// ---------------- BN1 stats: per-block partials (deterministic) ----------------
__global__ __launch_bounds__(256) void k_stats1(const float* __restrict__ y1,
                                                float* __restrict__ part) {
  int t = threadIdx.x;
  int c = t & 63;
  float s = 0.f, q = 0.f;
  for (int row = blockIdx.x * 4 + (t >> 6); row < B_ * S_ * K_; row += 512 * 4) {
    float v = y1[(size_t)row * 64 + c];
    s += v;
    q = fmaf(v, v, q);
  }
  __shared__ float ls[4][64], lq[4][64];
  ls[t >> 6][c] = s;
  lq[t >> 6][c] = q;
  __syncthreads();
  if (t < 64) {
    float S = (ls[0][t] + ls[1][t]) + (ls[2][t] + ls[3][t]);
    float Q = (lq[0][t] + lq[1][t]) + (lq[2][t] + lq[3][t]);
    part[blockIdx.x * 128 + t] = S;
    part[blockIdx.x * 128 + 64 + t] = Q;
  }
}

// ---------------- reduce [nrow][ncol] partials -> [ncol] ----------------
__global__ void k_red(const float* __restrict__ part, float* __restrict__ outv,
                      int ncol, int nrow) {
  int c = blockIdx.x * 64 + threadIdx.x;
  float a0 = 0, a1 = 0, a2 = 0, a3 = 0;
  for (int r = 0; r < nrow; r += 4) {
    a0 += part[(size_t)(r + 0) * ncol + c];
    a1 += part[(size_t)(r + 1) * ncol + c];
    a2 += part[(size_t)(r + 2) * ncol + c];
    a3 += part[(size_t)(r + 3) * ncol + c];
  }
  outv[c] = (a0 + a1) + (a2 + a3);
}

// ------- BN1-apply + conv2 (64->128) + stats2 partials + max/min over K -------
__global__ __launch_bounds__(256) void k_conv2(const float* __restrict__ y1,
                                               const float* __restrict__ W1,
                                               const float* __restrict__ st1,
                                               const float* __restrict__ g0,
                                               const float* __restrict__ b0,
                                               float* __restrict__ part2,
                                               float* __restrict__ mmax,
                                               float* __restrict__ mmin) {
  __shared__ float w1t[64][128];
  __shared__ float X2[32][69];
  __shared__ float a1s[64], bb1s[64];
  const int t = threadIdx.x;
  if (t < 64) {
    float s = st1[t], q = st1[64 + t];
    float m = s * (1.f / 131072.f);
    float v = fmaxf(q * (1.f / 131072.f) - m * m, 0.f);
    float inv = 1.f / sqrtf(v + 1e-5f);
    float a = g0[t] * inv;
    a1s[t] = a;
    bb1s[t] = b0[t] - m * a;
  }
  for (int idx = t; idx < 64 * 128; idx += 256) {
    int i = idx >> 7, c = idx & 127;
    w1t[i][c] = W1[c * 64 + i];
  }
  const int kg = (t & 7) << 2;   // 4 neighbor slots
  const int cb = (t >> 3) << 2;  // 4 channels
  const int gk = t >> 3, c8 = (t & 7) << 3;
  float ts[4] = {}, tq[4] = {};
  for (int cc = 0; cc < 8; ++cc) {
    int cs = blockIdx.x * 8 + cc;
    int b = cs >> 10, sc = cs & 1023;
    __syncthreads();
    {
      const float* src = y1 + ((size_t)cs * K_ + gk) * 64 + c8;
      float4 v0 = *(const float4*)src;
      float4 v1 = *(const float4*)(src + 4);
      float vv[8] = {v0.x, v0.y, v0.z, v0.w, v1.x, v1.y, v1.z, v1.w};
#pragma unroll
      for (int j = 0; j < 8; ++j) {
        int c = c8 + j;
        X2[gk][c] = fmaxf(fmaf(a1s[c], vv[j], bb1s[c]), 0.f);
      }
    }
    __syncthreads();
    float acc[4][4] = {};
    for (int i = 0; i < 64; ++i) {
      const float4 w = *(const float4*)&w1t[i][cb];
#pragma unroll
      for (int kk = 0; kk < 4; ++kk) {
        float xv = X2[kg + kk][i];
        acc[kk][0] = fmaf(w.x, xv, acc[kk][0]);
        acc[kk][1] = fmaf(w.y, xv, acc[kk][1]);
        acc[kk][2] = fmaf(w.z, xv, acc[kk][2]);
        acc[kk][3] = fmaf(w.w, xv, acc[kk][3]);
      }
    }
    float mx[4], mn[4];
#pragma unroll
    for (int j = 0; j < 4; ++j) {
      mx[j] = fmaxf(fmaxf(acc[0][j], acc[1][j]), fmaxf(acc[2][j], acc[3][j]));
      mn[j] = fminf(fminf(acc[0][j], acc[1][j]), fminf(acc[2][j], acc[3][j]));
      ts[j] += (acc[0][j] + acc[1][j]) + (acc[2][j] + acc[3][j]);
      tq[j] += (acc[0][j] * acc[0][j] + acc[1][j] * acc[1][j]) +
               (acc[2][j] * acc[2][j] + acc[3][j] * acc[3][j]);
    }
#pragma unroll
    for (int off = 1; off < 8; off <<= 1) {
#pragma unroll
      for (int j = 0; j < 4; ++j) {
        mx[j] = fmaxf(mx[j], __shfl_xor(mx[j], off));
        mn[j] = fminf(mn[j], __shfl_xor(mn[j], off));
      }
    }
    if ((t & 7) == 0) {
#pragma unroll
      for (int j = 0; j < 4; ++j) {
        size_t o = ((size_t)b * 128 + cb + j) * 1024 + sc;
        mmax[o] = mx[j];
        mmin[o] = mn[j];
      }
    }
  }
#pragma unroll
  for (int off = 1; off < 8; off <<= 1) {
#pragma unroll
    for (int j = 0; j < 4; ++j) {
      ts[j] += __shfl_xor(ts[j], off);
      tq[j] += __shfl_xor(tq[j], off);
    }
  }
  if ((t & 7) == 0) {
#pragma unroll
    for (int j = 0; j < 4; ++j) {
      part2[blockIdx.x * 256 + cb + j] = ts[j];
      part2[blockIdx.x * 256 + 128 + cb + j] = tq[j];
    }
  }
}

// ---------------- finalize: BN2 affine on max/min + ReLU ----------------
__global__ __launch_bounds__(256) void k_final(const float* __restrict__ st2,
                                               const float* __restrict__ g1,
                                               const float* __restrict__ b1,
                                               const float* __restrict__ mmax,
                                               const float* __restrict__ mmin,
                                               float* __restrict__ out) {
  int tid = blockIdx.x * 256 + threadIdx.x;
  int c = (tid >> 10) & 127;
  float s = st2[c], q = st2[128 + c];
  float m = s * (1.f / 131072.f);
  float v = fmaxf(q * (1.f / 131072.f) - m * m, 0.f);
  float inv = 1.f / sqrtf(v + 1e-5f);
  float a = g1[c] * inv;
  float bb = b1[c] - m * a;
  // max over K of relu(a*x+bb) == relu(a * (a>=0 ? max : min) + bb)
  float x = (a >= 0.f) ? mmax[tid] : mmin[tid];
  out[12288 + tid] = fmaxf(fmaf(a, x, bb), 0.f);
}

extern "C" void kernel_launch(void* const* d_in, const int* in_sizes, int n_in,
                              void* d_out, int out_size, void* d_ws, size_t ws_size,
                              hipStream_t stream) {
  const float* xyz = (const float*)d_in[0];
  const float* features = (const float*)d_in[1];
  const float* W0 = (const float*)d_in[2];
  const float* g0 = (const float*)d_in[3];
  const float* b0 = (const float*)d_in[4];
  const float* W1 = (const float*)d_in[5];
  const float* g1 = (const float*)d_in[6];
  const float* b1 = (const float*)d_in[7];
  float* out = (float*)d_out;
  float* ws = (float*)d_ws;

  float* ft = ws;                                   // 4,194,304 f
  float* y1 = ft + (size_t)4 * 16384 * 64;          // 8,388,608 f
  float* part1 = y1 + (size_t)4 * 1024 * 32 * 64;   // 65,536 f
  float* part2 = part1 + 512 * 128;                 // 131,072 f
  float* st1 = part2 + 512 * 256;                   // 128 f
  float* st2 = st1 + 128;                           // 256 f
  float* mmax = st2 + 256;                          // 524,288 f
  float* mmin = mmax + (size_t)4 * 128 * 1024;      // 524,288 f
  int* bidx = (int*)(mmin + (size_t)4 * 128 * 1024);// 131,072 i
  if (ws_size < (size_t)(13828480 + 131072) * 4) return;  // workspace guard

  float* nxyz = out;  // new_xyz occupies out[0..12288)

  k_transpose<<<1024, 256, 0, stream>>>(features, ft);
  k_fps<<<4, 1024, 0, stream>>>(xyz, nxyz);
  k_ball<<<1024, 256, 0, stream>>>(xyz, nxyz, bidx);
  k_conv1<<<512, 256, 0, stream>>>(xyz, ft, nxyz, bidx, W0, y1);
  k_stats1<<<512, 256, 0, stream>>>(y1, part1);
  k_red<<<2, 64, 0, stream>>>(part1, st1, 128, 512);
  k_conv2<<<512, 256, 0, stream>>>(y1, W1, st1, g0, b0, part2, mmax, mmin);
  k_red<<<4, 64, 0, stream>>>(part2, st2, 256, 512);
  k_final<<<2048, 256, 0, stream>>>(st2, g1, b1, mmax, mmin, out);
}

// Round 13
// 1534.203 us; speedup vs baseline: 1.9841x; 1.3600x over previous
//
#include <hip/hip_runtime.h>
#include <hip/hip_bf16.h>

#define B_ 4
#define N_ 16384
#define S_ 1024
#define K_ 32

typedef float f32x2 __attribute__((ext_vector_type(2)));

// wave64 max of nonnegative floats via DPP (identity 0 from bound_ctrl fill).
__device__ __forceinline__ float wave_max_nonneg(float x) {
#define DPPSTEP(ctrl, rm)                                                              \
  {                                                                                    \
    int s_ = __builtin_amdgcn_update_dpp(__float_as_int(x), __float_as_int(x), (ctrl), \
                                         (rm), 0xf, true);                             \
    x = fmaxf(x, __int_as_float(s_));                                                  \
  }
  DPPSTEP(0x111, 0xf)  // row_shr:1
  DPPSTEP(0x112, 0xf)  // row_shr:2
  DPPSTEP(0x114, 0xf)  // row_shr:4
  DPPSTEP(0x118, 0xf)  // row_shr:8
  DPPSTEP(0x142, 0xa)  // row_bcast:15 -> rows 1,3
  DPPSTEP(0x143, 0xc)  // row_bcast:31 -> rows 2,3
#undef DPPSTEP
  return __int_as_float(__builtin_amdgcn_readlane(__float_as_int(x), 63));
}

// ---------------- transpose features [B,64,N] -> [B,N,64] ----------------
__global__ __launch_bounds__(256) void k_transpose(const float* __restrict__ f,
                                                   float* __restrict__ ft) {
  __shared__ float tile[64][65];
  int b = blockIdx.x >> 8;
  int n0 = (blockIdx.x & 255) << 6;
  int t = threadIdx.x;
  int r = t >> 6, c = t & 63;
#pragma unroll
  for (int i = 0; i < 16; ++i) {
    int ch = r + i * 4;
    tile[ch][c] = f[((size_t)b * 64 + ch) * N_ + n0 + c];
  }
  __syncthreads();
#pragma unroll
  for (int i = 0; i < 16; ++i) {
    int n = r + i * 4;
    ft[((size_t)b * N_ + n0 + n) * 64 + c] = tile[c][n];
  }
}

// ---------------- furthest point sampling with EXACT pruning ----------------
// QuickFPS-style chunk pruning: md only decreases, so for a 16-point chunk
// with bbox B and cached lmax=max(md), dmin(center,B)^2 * 0.999 > lmax proves
// (with float-error margin 1e-3 >> 1e-6) that no md in the chunk changes ->
// skip the update AND replay the cached argmax candidate. Counting-sort by
// 4x4x4 cell (one-time, into global scratch) makes chunks spatially tight.
// Candidate packing {md_bits:32, ~(orig<<14|pos):28} keeps np.argmax
// first-max (min ORIGINAL index) semantics exactly, independent of the
// (run-varying) sort order. md values themselves are bit-exact: skipped
// chunks provably unchanged, updated chunks use the proven round-6 formula.
__global__ __attribute__((amdgpu_flat_work_group_size(1024, 1024)))
__attribute__((amdgpu_waves_per_eu(4, 4))) void k_fps(const float* __restrict__ xyz,
                                                      float* __restrict__ out,
                                                      float4* __restrict__ S4all) {
#pragma clang fp contract(off)
  const int b = blockIdx.x, t = threadIdx.x;
  const float* X = xyz + (size_t)b * N_ * 3;
  float4* S4 = S4all + (size_t)b * N_;

  __shared__ unsigned hist[64], cfill[64];
  __shared__ unsigned long long slot64[2];

  if (t < 64) hist[t] = 0u;
  if (t == 0) { slot64[0] = 0ull; slot64[1] = 0ull; }
  __syncthreads();

  // phase A: cell histogram
  unsigned mycell[16];
#pragma unroll
  for (int q = 0; q < 16; ++q) {
    int p = (q << 10) + t;
    float x = X[p * 3], y = X[p * 3 + 1], z = X[p * 3 + 2];
    int cx = (int)(x * 4.f); cx = cx > 3 ? 3 : cx;
    int cy = (int)(y * 4.f); cy = cy > 3 ? 3 : cy;
    int cz = (int)(z * 4.f); cz = cz > 3 ? 3 : cz;
    mycell[q] = ((unsigned)cx << 4) | ((unsigned)cy << 2) | (unsigned)cz;
    atomicAdd(&hist[mycell[q]], 1u);
  }
  __syncthreads();
  // phase B: exclusive prefix -> cfill
  if (t == 0) {
    unsigned s = 0;
    for (int i = 0; i < 64; ++i) { unsigned h = hist[i]; cfill[i] = s; s += h; }
  }
  __syncthreads();
  // phase C: scatter sorted {x,y,z,orig} to global scratch
#pragma unroll
  for (int q = 0; q < 16; ++q) {
    int p = (q << 10) + t;
    float x = X[p * 3], y = X[p * 3 + 1], z = X[p * 3 + 2];
    unsigned pos = atomicAdd(&cfill[mycell[q]], 1u);
    S4[pos] = make_float4(x, y, z, __uint_as_float((unsigned)p));
  }
  __threadfence();
  __syncthreads();

  // phase D: gather my contiguous 16 sorted points into registers + bbox
  f32x2 px0, px1, px2, px3, px4, px5, px6, px7;
  f32x2 py0, py1, py2, py3, py4, py5, py6, py7;
  f32x2 pz0, pz1, pz2, pz3, pz4, pz5, pz6, pz7;
  f32x2 md0, md1, md2, md3, md4, md5, md6, md7;
  unsigned oi0, oi1, oi2, oi3, oi4, oi5, oi6, oi7;
  const int base = t << 4;
#define LOADP(j)                                                     \
  {                                                                  \
    float4 a = S4[base + 2 * j], c = S4[base + 2 * j + 1];           \
    px##j = (f32x2){a.x, c.x};                                       \
    py##j = (f32x2){a.y, c.y};                                       \
    pz##j = (f32x2){a.z, c.z};                                       \
    oi##j = (__float_as_uint(a.w) << 16) | (__float_as_uint(c.w) & 0xFFFFu); \
    md##j = (f32x2){1e10f, 1e10f};                                   \
  }
  LOADP(0) LOADP(1) LOADP(2) LOADP(3) LOADP(4) LOADP(5) LOADP(6) LOADP(7)
#undef LOADP
#define EMIN __builtin_elementwise_min
#define EMAX __builtin_elementwise_max
  f32x2 tmn = EMIN(EMIN(EMIN(px0, px1), EMIN(px2, px3)), EMIN(EMIN(px4, px5), EMIN(px6, px7)));
  f32x2 tmx = EMAX(EMAX(EMAX(px0, px1), EMAX(px2, px3)), EMAX(EMAX(px4, px5), EMAX(px6, px7)));
  float bxmin = fminf(tmn.x, tmn.y), bxmax = fmaxf(tmx.x, tmx.y);
  tmn = EMIN(EMIN(EMIN(py0, py1), EMIN(py2, py3)), EMIN(EMIN(py4, py5), EMIN(py6, py7)));
  tmx = EMAX(EMAX(EMAX(py0, py1), EMAX(py2, py3)), EMAX(EMAX(py4, py5), EMAX(py6, py7)));
  float bymin = fminf(tmn.x, tmn.y), bymax = fmaxf(tmx.x, tmx.y);
  tmn = EMIN(EMIN(EMIN(pz0, pz1), EMIN(pz2, pz3)), EMIN(EMIN(pz4, pz5), EMIN(pz6, pz7)));
  tmx = EMAX(EMAX(EMAX(pz0, pz1), EMAX(pz2, pz3)), EMAX(EMAX(pz4, pz5), EMAX(pz6, pz7)));
  float bzmin = fminf(tmn.x, tmn.y), bzmax = fmaxf(tmx.x, tmx.y);

  float lmax = 1e10f;                 // cached max of my 16 md (exact)
  unsigned long long wcand = 0ull;    // cached candidate (candidate lanes only)

  float c0x = X[0], c0y = X[1], c0z = X[2];
  f32x2 ncx = (f32x2){-c0x, -c0x};
  f32x2 ncy = (f32x2){-c0y, -c0y};
  f32x2 ncz = (f32x2){-c0z, -c0z};

  int sld = 0;
  for (int it = 0;; ++it) {
    if (t == 0) {
      float* o = out + ((size_t)b * S_ + it) * 3;
      o[0] = -ncx.x; o[1] = -ncy.x; o[2] = -ncz.x;
    }
    if (it == S_ - 1) break;

    // chunk prune test: provably-safe skip (slack 1e-3 >> fp error ~1e-6)
    float ccx = -ncx.x, ccy = -ncy.x, ccz = -ncz.x;
    float dxm = fmaxf(fmaxf(bxmin - ccx, ccx - bxmax), 0.f);
    float dym = fmaxf(fmaxf(bymin - ccy, ccy - bymax), 0.f);
    float dzm = fmaxf(fmaxf(bzmin - ccz, ccz - bzmax), 0.f);
    float dmin2 = (dxm * dxm + dym * dym) + dzm * dzm;
    bool needs = !(dmin2 * 0.999f > lmax);
    unsigned long long mball = __ballot(needs);

    if (mball) {  // wave-uniform
      if (needs) {
#define FPS_UPD(j)                                  \
  {                                                 \
    f32x2 dx = px##j + ncx;                         \
    f32x2 dy = py##j + ncy;                         \
    f32x2 dz = pz##j + ncz;                         \
    f32x2 ss = (dx * dx + dy * dy) + dz * dz;       \
    md##j = EMIN(md##j, ss);                        \
  }
        FPS_UPD(0) FPS_UPD(1) FPS_UPD(2) FPS_UPD(3)
        FPS_UPD(4) FPS_UPD(5) FPS_UPD(6) FPS_UPD(7)
#undef FPS_UPD
        f32x2 m01 = EMAX(md0, md1), m23 = EMAX(md2, md3);
        f32x2 m45 = EMAX(md4, md5), m67 = EMAX(md6, md7);
        f32x2 mm = EMAX(EMAX(m01, m23), EMAX(m45, m67));
        lmax = fmaxf(mm.x, mm.y);
      }
      float wm = wave_max_nonneg(lmax);  // full-exec DPP reduce
      if (lmax == wm) {
        // min ORIGINAL index among my slots attaining wm
        unsigned bestX = 0xFFFFFFFFu;
#define SCANS(j)                                                              \
  {                                                                           \
    unsigned oA = oi##j >> 16;                                                \
    unsigned XA = (oA << 14) | (unsigned)(base + 2 * j);                      \
    if (md##j.x == wm && XA < bestX) bestX = XA;                              \
    unsigned oB = oi##j & 0xFFFFu;                                            \
    unsigned XB = (oB << 14) | (unsigned)(base + 2 * j + 1);                  \
    if (md##j.y == wm && XB < bestX) bestX = XB;                              \
  }
        SCANS(0) SCANS(1) SCANS(2) SCANS(3) SCANS(4) SCANS(5) SCANS(6) SCANS(7)
#undef SCANS
        unsigned long long cand =
            ((unsigned long long)__float_as_uint(wm) << 28) |
            (unsigned long long)((~bestX) & 0xFFFFFFFu);
        atomicMax(&slot64[sld], cand);
        wcand = cand;
      } else {
        wcand = 0ull;
      }
    } else {
      if (wcand) atomicMax(&slot64[sld], wcand);  // replay cached (exact: nothing changed)
    }
    if (t == 0) slot64[sld ^ 1] = 0ull;  // reset next slot before the barrier
    __syncthreads();

    unsigned long long pkv = slot64[sld];
    unsigned low = (unsigned)(pkv & 0xFFFFFFFull);
    unsigned Xv = 0xFFFFFFFu ^ low;       // (orig<<14)|pos of winner
    unsigned pos = Xv & 16383u;
    float4 cw = S4[pos];                  // uniform broadcast load (L2-hot)
    ncx = (f32x2){-cw.x, -cw.x};
    ncy = (f32x2){-cw.y, -cw.y};
    ncz = (f32x2){-cw.z, -cw.z};
    sld ^= 1;
  }
#undef EMIN
#undef EMAX
}

// ---------------- ball query: 1 wave per center ----------------
__global__ __launch_bounds__(256) void k_ball(const float* __restrict__ xyz,
                                              const float* __restrict__ nx,
                                              int* __restrict__ bidx) {
#pragma clang fp contract(off)
  int gw = (blockIdx.x * 256 + threadIdx.x) >> 6;
  int l = threadIdx.x & 63;
  int b = gw >> 10;
  const float* X = xyz + (size_t)b * N_ * 3;
  float cx = nx[(size_t)gw * 3 + 0], cy = nx[(size_t)gw * 3 + 1], cz = nx[(size_t)gw * 3 + 2];
  float xn2 = (cx * cx + cy * cy) + cz * cz;
  int* out = bidx + gw * K_;
  int have = 0, first = -1;
  for (int n0 = 0; n0 < N_; n0 += 64) {
    int p = n0 + l;
    float x = X[p * 3 + 0], y = X[p * 3 + 1], z = X[p * 3 + 2];
    float pn2 = (x * x + y * y) + z * z;
    float dt = (x * cx + y * cy) + z * cz;
    float d2 = (xn2 + pn2) - 2.0f * dt;  // exact replica of ref's expanded form
    unsigned long long m = __ballot(d2 < 0.039999999105930328f);  // float(0.04), NOT 0.2f*0.2f
    if (first < 0 && m) first = n0 + (__ffsll(m) - 1);
    if (m & (1ull << l)) {
      int pos = have + __popcll(m & ((1ull << l) - 1ull));
      if (pos < K_) out[pos] = p;
    }
    have += __popcll(m);
    if (have >= K_) break;
  }
  if (have < K_ && l >= have && l < K_) out[l] = first;  // pad with first neighbor
}

// ---------------- gather + conv1 (67 -> 64), 8 centers per block ----------------
__global__ __launch_bounds__(256) void k_conv1(const float* __restrict__ xyz,
                                               const float* __restrict__ ft,
                                               const float* __restrict__ nx,
                                               const int* __restrict__ bidx,
                                               const float* __restrict__ W0,
                                               float* __restrict__ y1) {
  __shared__ float w0t[67][64];
  __shared__ float Xs[32][69];  // stride 69: (69k+i)%32 = (5k+i)%32 conflict-free
  __shared__ int lidx[32];
  __shared__ float lctr[3];
  const int t = threadIdx.x;
  for (int idx = t; idx < 67 * 64; idx += 256) {
    int i = idx >> 6, c = idx & 63;
    w0t[i][c] = W0[c * 67 + i];
  }
  const int k = t & 31, cb = (t >> 5) << 3;
  const int gk = t >> 3, c8 = (t & 7) << 3;
  for (int cc = 0; cc < 8; ++cc) {
    int cs = blockIdx.x * 8 + cc;
    int b = cs >> 10;
    __syncthreads();
    if (t < 32) lidx[t] = bidx[cs * K_ + t];
    if (t < 3) lctr[t] = nx[(size_t)cs * 3 + t];
    __syncthreads();
    {
      int p = lidx[gk];
      const float* src = ft + ((size_t)b * N_ + p) * 64 + c8;
      float4 v0 = *(const float4*)src;
      float4 v1 = *(const float4*)(src + 4);
      float* xr = &Xs[gk][3 + c8];
      xr[0] = v0.x; xr[1] = v0.y; xr[2] = v0.z; xr[3] = v0.w;
      xr[4] = v1.x; xr[5] = v1.y; xr[6] = v1.z; xr[7] = v1.w;
    }
    if (t < 32) {
      int p = lidx[t];
      const float* pp = xyz + ((size_t)b * N_ + p) * 3;
      Xs[t][0] = pp[0] - lctr[0];
      Xs[t][1] = pp[1] - lctr[1];
      Xs[t][2] = pp[2] - lctr[2];
    }
    __syncthreads();
    float acc[8] = {};
    for (int i = 0; i < 67; ++i) {
      float xv = Xs[k][i];
      const float4 wa = *(const float4*)&w0t[i][cb];
      const float4 wb = *(const float4*)&w0t[i][cb + 4];
      acc[0] = fmaf(wa.x, xv, acc[0]);
      acc[1] = fmaf(wa.y, xv, acc[1]);
      acc[2] = fmaf(wa.z, xv, acc[2]);
      acc[3] = fmaf(wa.w, xv, acc[3]);
      acc[4] = fmaf(wb.x, xv, acc[4]);
      acc[5] = fmaf(wb.y, xv, acc[5]);
      acc[6] = fmaf(wb.z, xv, acc[6]);
      acc[7] = fmaf(wb.w, xv, acc[7]);
    }
    float* dst = y1 + ((size_t)cs * K_ + k) * 64 + cb;
    *(float4*)dst = make_float4(acc[0], acc[1], acc[2], acc[3]);
    *(float4*)(dst + 4) = make_float4(acc[4], acc[5], acc[6], acc[7]);
  }
}

// ---------------- BN1 stats: per-block partials (deterministic) ----------------
__global__ __launch_bounds__(256) void k_stats1(const float* __restrict__ y1,
                                                float* __restrict__ part) {
  int t = threadIdx.x;
  int c = t & 63;
  float s = 0.f, q = 0.f;
  for (int row = blockIdx.x * 4 + (t >> 6); row < B_ * S_ * K_; row += 512 * 4) {
    float v = y1[(size_t)row * 64 + c];
    s += v;
    q = fmaf(v, v, q);
  }
  __shared__ float ls[4][64], lq[4][64];
  ls[t >> 6][c] = s;
  lq[t >> 6][c] = q;
  __syncthreads();
  if (t < 64) {
    float S = (ls[0][t] + ls[1][t]) + (ls[2][t] + ls[3][t]);
    float Q = (lq[0][t] + lq[1][t]) + (lq[2][t] + lq[3][t]);
    part[blockIdx.x * 128 + t] = S;
    part[blockIdx.x * 128 + 64 + t] = Q;
  }
}

// ---------------- reduce [nrow][ncol] partials -> [ncol] ----------------
__global__ void k_red(const float* __restrict__ part, float* __restrict__ outv,
                      int ncol, int nrow) {
  int c = blockIdx.x * 64 + threadIdx.x;
  float a0 = 0, a1 = 0, a2 = 0, a3 = 0;
  for (int r = 0; r < nrow; r += 4) {
    a0 += part[(size_t)(r + 0) * ncol + c];
    a1 += part[(size_t)(r + 1) * ncol + c];
    a2 += part[(size_t)(r + 2) * ncol + c];
    a3 += part[(size_t)(r + 3) * ncol + c];
  }
  outv[c] = (a0 + a1) + (a2 + a3);
}

// ------- BN1-apply + conv2 (64->128) + stats2 partials + max/min over K -------
__global__ __launch_bounds__(256) void k_conv2(const float* __restrict__ y1,
                                               const float* __restrict__ W1,
                                               const float* __restrict__ st1,
                                               const float* __restrict__ g0,
                                               const float* __restrict__ b0,
                                               float* __restrict__ part2,
                                               float* __restrict__ mmax,
                                               float* __restrict__ mmin) {
  __shared__ float w1t[64][128];
  __shared__ float X2[32][69];
  __shared__ float a1s[64], bb1s[64];
  const int t = threadIdx.x;
  if (t < 64) {
    float s = st1[t], q = st1[64 + t];
    float m = s * (1.f / 131072.f);
    float v = fmaxf(q * (1.f / 131072.f) - m * m, 0.f);
    float inv = 1.f / sqrtf(v + 1e-5f);
    float a = g0[t] * inv;
    a1s[t] = a;
    bb1s[t] = b0[t] - m * a;
  }
  for (int idx = t; idx < 64 * 128; idx += 256) {
    int i = idx >> 7, c = idx & 127;
    w1t[i][c] = W1[c * 64 + i];
  }
  const int kg = (t & 7) << 2;   // 4 neighbor slots
  const int cb = (t >> 3) << 2;  // 4 channels
  const int gk = t >> 3, c8 = (t & 7) << 3;
  float ts[4] = {}, tq[4] = {};
  for (int cc = 0; cc < 8; ++cc) {
    int cs = blockIdx.x * 8 + cc;
    int b = cs >> 10, sc = cs & 1023;
    __syncthreads();
    {
      const float* src = y1 + ((size_t)cs * K_ + gk) * 64 + c8;
      float4 v0 = *(const float4*)src;
      float4 v1 = *(const float4*)(src + 4);
      float vv[8] = {v0.x, v0.y, v0.z, v0.w, v1.x, v1.y, v1.z, v1.w};
#pragma unroll
      for (int j = 0; j < 8; ++j) {
        int c = c8 + j;
        X2[gk][c] = fmaxf(fmaf(a1s[c], vv[j], bb1s[c]), 0.f);
      }
    }
    __syncthreads();
    float acc[4][4] = {};
    for (int i = 0; i < 64; ++i) {
      const float4 w = *(const float4*)&w1t[i][cb];
#pragma unroll
      for (int kk = 0; kk < 4; ++kk) {
        float xv = X2[kg + kk][i];
        acc[kk][0] = fmaf(w.x, xv, acc[kk][0]);
        acc[kk][1] = fmaf(w.y, xv, acc[kk][1]);
        acc[kk][2] = fmaf(w.z, xv, acc[kk][2]);
        acc[kk][3] = fmaf(w.w, xv, acc[kk][3]);
      }
    }
    float mx[4], mn[4];
#pragma unroll
    for (int j = 0; j < 4; ++j) {
      mx[j] = fmaxf(fmaxf(acc[0][j], acc[1][j]), fmaxf(acc[2][j], acc[3][j]));
      mn[j] = fminf(fminf(acc[0][j], acc[1][j]), fminf(acc[2][j], acc[3][j]));
      ts[j] += (acc[0][j] + acc[1][j]) + (acc[2][j] + acc[3][j]);
      tq[j] += (acc[0][j] * acc[0][j] + acc[1][j] * acc[1][j]) +
               (acc[2][j] * acc[2][j] + acc[3][j] * acc[3][j]);
    }
#pragma unroll
    for (int off = 1; off < 8; off <<= 1) {
#pragma unroll
      for (int j = 0; j < 4; ++j) {
        mx[j] = fmaxf(mx[j], __shfl_xor(mx[j], off));
        mn[j] = fminf(mn[j], __shfl_xor(mn[j], off));
      }
    }
    if ((t & 7) == 0) {
#pragma unroll
      for (int j = 0; j < 4; ++j) {
        size_t o = ((size_t)b * 128 + cb + j) * 1024 + sc;
        mmax[o] = mx[j];
        mmin[o] = mn[j];
      }
    }
  }
#pragma unroll
  for (int off = 1; off < 8; off <<= 1) {
#pragma unroll
    for (int j = 0; j < 4; ++j) {
      ts[j] += __shfl_xor(ts[j], off);
      tq[j] += __shfl_xor(tq[j], off);
    }
  }
  if ((t & 7) == 0) {
#pragma unroll
    for (int j = 0; j < 4; ++j) {
      part2[blockIdx.x * 256 + cb + j] = ts[j];
      part2[blockIdx.x * 256 + 128 + cb + j] = tq[j];
    }
  }
}

// ---------------- finalize: BN2 affine on max/min + ReLU ----------------
__global__ __launch_bounds__(256) void k_final(const float* __restrict__ st2,
                                               const float* __restrict__ g1,
                                               const float* __restrict__ b1,
                                               const float* __restrict__ mmax,
                                               const float* __restrict__ mmin,
                                               float* __restrict__ out) {
  int tid = blockIdx.x * 256 + threadIdx.x;
  int c = (tid >> 10) & 127;
  float s = st2[c], q = st2[128 + c];
  float m = s * (1.f / 131072.f);
  float v = fmaxf(q * (1.f / 131072.f) - m * m, 0.f);
  float inv = 1.f / sqrtf(v + 1e-5f);
  float a = g1[c] * inv;
  float bb = b1[c] - m * a;
  // max over K of relu(a*x+bb) == relu(a * (a>=0 ? max : min) + bb)
  float x = (a >= 0.f) ? mmax[tid] : mmin[tid];
  out[12288 + tid] = fmaxf(fmaf(a, x, bb), 0.f);
}

extern "C" void kernel_launch(void* const* d_in, const int* in_sizes, int n_in,
                              void* d_out, int out_size, void* d_ws, size_t ws_size,
                              hipStream_t stream) {
  const float* xyz = (const float*)d_in[0];
  const float* features = (const float*)d_in[1];
  const float* W0 = (const float*)d_in[2];
  const float* g0 = (const float*)d_in[3];
  const float* b0 = (const float*)d_in[4];
  const float* W1 = (const float*)d_in[5];
  const float* g1 = (const float*)d_in[6];
  const float* b1 = (const float*)d_in[7];
  float* out = (float*)d_out;
  float* ws = (float*)d_ws;

  float* ft = ws;                                   // 4,194,304 f
  float* y1 = ft + (size_t)4 * 16384 * 64;          // 8,388,608 f (also k_fps sort scratch)
  float* part1 = y1 + (size_t)4 * 1024 * 32 * 64;   // 65,536 f
  float* part2 = part1 + 512 * 128;                 // 131,072 f
  float* st1 = part2 + 512 * 256;                   // 128 f
  float* st2 = st1 + 128;                           // 256 f
  float* mmax = st2 + 256;                          // 524,288 f
  float* mmin = mmax + (size_t)4 * 128 * 1024;      // 524,288 f
  int* bidx = (int*)(mmin + (size_t)4 * 128 * 1024);// 131,072 i
  if (ws_size < (size_t)(13828480 + 131072) * 4) return;  // workspace guard

  float* nxyz = out;  // new_xyz occupies out[0..12288)

  k_transpose<<<1024, 256, 0, stream>>>(features, ft);
  k_fps<<<4, 1024, 0, stream>>>(xyz, nxyz, (float4*)y1);  // y1 free until k_conv1
  k_ball<<<1024, 256, 0, stream>>>(xyz, nxyz, bidx);
  k_conv1<<<512, 256, 0, stream>>>(xyz, ft, nxyz, bidx, W0, y1);
  k_stats1<<<512, 256, 0, stream>>>(y1, part1);
  k_red<<<2, 64, 0, stream>>>(part1, st1, 128, 512);
  k_conv2<<<512, 256, 0, stream>>>(y1, W1, st1, g0, b0, part2, mmax, mmin);
  k_red<<<4, 64, 0, stream>>>(part2, st2, 256, 512);
  k_final<<<2048, 256, 0, stream>>>(st2, g1, b1, mmax, mmin, out);
}